// Round 20
// baseline (26.026 us; speedup 1.0000x reference)
//
#include <hip/hip_runtime.h>

// LBP forward: out[n,f,h,w] = sum_p 2^p * sigmoid((nb - ctr)/0.1)
//   c  = projection_map[f,p]; ky,kx = kernels[f,p,:] in {0,1,2}
//   nb  = xpad[n,c,h+ky-1,w+kx-1]  (zero pad of 1), ctr = x[n,c,h,w]
// N=32 D=64 H=56 W=56 F=128 P=4
//
// Round-20 = r19's packed-pair compute with the staging redundancy removed.
// r19 post-mortem: packed fp16 image-pairs halved compute (~9.5us) but the
// z=2 f-split double-fetched every tile (66MB, twins race -> no L2 absorb);
// stage exposure ~13us dominated. Here: NO f-split (each block does all 128
// f), block = (pair, 4-row strip): grid 16x14 = 224 blocks, tile 64ch x
// 6rows x 64cols of half2 = 98.3KB -> 1 block/CU. Stage/block = 172KB,
// chip total 38.5MB fetched ONCE. Compute per block ~= r19 (same f-iters x
// fewer rows). pair%8 XCD pin keeps inter-strip halo re-reads L2-local
// (2 pairs x 2 imgs = 3.2MB < 4MB L2/XCD).
// Center taps (ky==kx==1) fold to wt/2 in acc init; reads+math skipped.
// Sigmoid: 3-tangent-line min (0.1875 proven) in packed v_pk_fma/min_f16.

#define NN 32
#define DD 64
#define HH 56
#define WW 56
#define FF 128
#define PP 4

#define ROWS 4          // output rows per block
#define TR   (ROWS + 2) // 6 tile rows incl. halo
#define TC   64         // padded cols (interior 4..59, zero pads at 3 and 60)
#define COL0 4
#define CHS  (TR * TC)  // 384 dwords per channel (dword = half2 image-pair)
#define TILE_DW (DD * CHS)   // 24576 dwords = 98304 B
#define NTHREADS 1024
#define NWAVES 16
#define NPAIR 16
#define NSTRIP (HH / ROWS)       // 14
#define FITER (FF / NWAVES)      // 8 f per wave
#define ITEMS (DD * TR * 14)     // 5376 staging items (2 float4 loads each)
#define NSLOT 6                  // ceil(5376/1024)
#define IMGSTR (DD * HH * WW)    // floats per image

typedef _Float16 h2 __attribute__((ext_vector_type(2)));

static __device__ __forceinline__ uint32_t h2u(h2 h) {
    union { h2 h; uint32_t u; } v; v.h = h; return v.u;
}
static __device__ __forceinline__ h2 u2h(uint32_t u) {
    union { h2 h; uint32_t u; } v; v.u = u; return v.h;
}
static __device__ __forceinline__ h2 splat(float f) {
    h2 r; r.x = (_Float16)f; r.y = (_Float16)f; return r;
}
static __device__ __forceinline__ uint32_t pack2(float a, float b) {
    h2 r; r.x = (_Float16)a; r.y = (_Float16)b; return h2u(r);
}

__global__ __launch_bounds__(NTHREADS, 4) void lbp_kernel(
    const float* __restrict__ x,    // (N,D,H,W)
    const int*   __restrict__ kern, // (F,P,2)
    const int*   __restrict__ proj, // (F,P)
    float*       __restrict__ out)  // (N,F,H,W)
{
    __shared__ uint32_t tile[TILE_DW];   // 98304 B, 1 block/CU

    const int tid = threadIdx.x;
    const int pr  = blockIdx.x;          // pair: images (pr, pr+16); XCD pin
    const int h0  = blockIdx.y * ROWS;   // 0,4,...,52

    const float* x0 = x + (size_t)pr * IMGSTR;
    const float* x1 = x0 + (size_t)NPAIR * IMGSTR;

    // ---- stage: 5376 items, 2 float4 loads each, all issued up front ----
    float4 av[NSLOT], bv[NSLOT];
    int    lo[NSLOT];
#pragma unroll
    for (int it = 0; it < NSLOT; ++it) {
        const int item = tid + it * NTHREADS;
        av[it] = make_float4(0.f, 0.f, 0.f, 0.f);
        bv[it] = make_float4(0.f, 0.f, 0.f, 0.f);
        lo[it] = -1;
        if (item < ITEMS) {                       // only it==5 is partial
            const int ch  = item / (TR * 14);
            const int rem = item - ch * (TR * 14);
            const int tr  = rem / 14;
            const int v   = rem - tr * 14;
            lo[it] = ch * CHS + tr * TC + COL0 + 4 * v;
            const int h = h0 + tr - 1;
            if ((unsigned)h < (unsigned)HH) {
                const int off = ch * (HH * WW) + h * WW + 4 * v;
                av[it] = *(const float4*)(x0 + off);
                bv[it] = *(const float4*)(x1 + off);
            }
        }
    }

    // ---- zero the kx-pad columns (3 and 60) while loads fly ----
    if (tid < DD * TR * 2) {
        const int side = tid & 1;
        const int cr   = tid >> 1;               // ch*TR + tr
        tile[cr * TC + (side ? 60 : 3)] = 0u;
    }

    // ---- pack (img0 = lo half, img1 = hi half) and land b128 ----
#pragma unroll
    for (int it = 0; it < NSLOT; ++it) {
        if (lo[it] >= 0) {
            uint4 q;
            q.x = pack2(av[it].x, bv[it].x);
            q.y = pack2(av[it].y, bv[it].y);
            q.z = pack2(av[it].z, bv[it].z);
            q.w = pack2(av[it].w, bv[it].w);
            *(uint4*)(tile + lo[it]) = q;        // 16B aligned (COL0+4v)
        }
    }
    __syncthreads();

    // ---- compute: wave = f-group, lane = column, 4 rows x 2 images ----
    const int wid  = __builtin_amdgcn_readfirstlane(tid >> 6);  // 0..15
    const int lane = tid & 63;
    const int w    = lane < WW ? lane : WW - 1;  // clamp idle lanes
    const bool act = lane < WW;
    const int cb   = TC + COL0 + w;              // ctr addr of output row 0

    const h2 K0a = splat(2.5f),     K0b = splat(-0.0078f);
    const h2 K1a = splat(1.49146f), K1b = splat(0.08455f);
    const h2 K2a = splat(0.45177f), K2b = splat(0.30774f);
    const h2 KF  = splat(0.49140f);
    const h2 INI = splat(7.5f);                  // sum wt*0.5 over all taps

    int f = wid;
    int4 pj = *(const int4*)(proj + f * PP);
    int4 ka = *(const int4*)(kern + f * (PP * 2));
    int4 kb = *(const int4*)(kern + f * (PP * 2) + 4);

#pragma unroll
    for (int k = 0; k < FITER; ++k) {
        const int fn = f + NWAVES;
        int4 pjn = pj, kan = ka, kbn = kb;       // initialized (no UB)
        if (k + 1 < FITER) {                     // one-ahead table prefetch
            pjn = *(const int4*)(proj + fn * PP);
            kan = *(const int4*)(kern + fn * (PP * 2));
            kbn = *(const int4*)(kern + fn * (PP * 2) + 4);
        }
        const int cc[4]  = {pj.x, pj.y, pj.z, pj.w};
        const int kyv[4] = {ka.x, ka.z, kb.x, kb.z};
        const int kxv[4] = {ka.y, ka.w, kb.y, kb.w};

        // ---- bulk packed reads: skip center taps; one lgkmcnt join ----
        uint32_t cu[PP][ROWS], nu[PP][ROWS];
#pragma unroll
        for (int p = 0; p < PP; ++p) {
            const int ky = kyv[p];               // wave-uniform
            const int kx = kxv[p];
            if (!(ky == 1 && kx == 1)) {
                const int pc = cc[p] * CHS + cb;               // ctr row 0
                const int pn = pc + (ky - 1) * TC + (kx - 1);  // neighbor
#pragma unroll
                for (int r = 0; r < ROWS; ++r) {
                    cu[p][r] = tile[pc + r * TC];
                    nu[p][r] = tile[pn + r * TC];
                }
            }
        }

        // ---- packed trans-free sigmoid ----
        h2 acc[ROWS];
#pragma unroll
        for (int r = 0; r < ROWS; ++r) acc[r] = INI;
#pragma unroll
        for (int p = 0; p < PP; ++p) {
            if (!(kyv[p] == 1 && kxv[p] == 1)) {
                const h2 wt2 = splat((float)(1 << p));
#pragma unroll
                for (int r = 0; r < ROWS; ++r) {
                    const h2 d  = u2h(nu[p][r]) - u2h(cu[p][r]);
                    const uint32_t du = h2u(d);
                    const h2 ad = u2h(du & 0x7FFF7FFFu);
                    const h2 u0 = __builtin_elementwise_fma(K0a, ad, K0b);
                    const h2 u1 = __builtin_elementwise_fma(K1a, ad, K1b);
                    const h2 u2 = __builtin_elementwise_fma(K2a, ad, K2b);
                    const h2 um = __builtin_elementwise_min(
                                      __builtin_elementwise_min(u0, u1),
                                      __builtin_elementwise_min(u2, KF));
                    const uint32_t su = (du & 0x80008000u)
                                      | (h2u(um) & 0x7FFF7FFFu);
                    acc[r] = __builtin_elementwise_fma(wt2, u2h(su), acc[r]);
                }
            }
        }

        if (act) {
            float* o0 = out + ((size_t)pr * FF + f) * (HH * WW)
                            + (size_t)h0 * WW + w;
            float* o1 = o0 + (size_t)NPAIR * FF * (HH * WW);
#pragma unroll
            for (int r = 0; r < ROWS; ++r) {
                o0[r * WW] = (float)acc[r].x;
                o1[r * WW] = (float)acc[r].y;
            }
        }
        f = fn; pj = pjn; ka = kan; kb = kbn;
    }
}

extern "C" void kernel_launch(void* const* d_in, const int* in_sizes, int n_in,
                              void* d_out, int out_size, void* d_ws, size_t ws_size,
                              hipStream_t stream) {
    const float* x    = (const float*)d_in[0];
    const int*   kern = (const int*)d_in[1];
    const int*   proj = (const int*)d_in[2];
    float*       out  = (float*)d_out;

    dim3 grid(NPAIR, NSTRIP);   // x = pair (XCD pin: id%8 = pair%8), y = strip
    dim3 block(NTHREADS);
    lbp_kernel<<<grid, block, 0, stream>>>(x, kern, proj, out);
}